// Round 10
// baseline (262.951 us; speedup 1.0000x reference)
//
#include <hip/hip_runtime.h>
#include <math.h>

#define D 64
#define B 64
#define NPB 128      // nodes per att block
#define NSLOT 4
#define SCAN_BS 1024

__device__ __forceinline__ unsigned encf(float x) {
  unsigned u = __float_as_uint(x);
  return (u & 0x80000000u) ? ~u : (u | 0x80000000u);
}
__device__ __forceinline__ float decf(unsigned e) {
  return (e & 0x80000000u) ? __uint_as_float(e ^ 0x80000000u) : __uint_as_float(~e);
}
__device__ __forceinline__ float sigm(float x) { return 1.0f / (1.0f + __expf(-x)); }

// ---------------- CSR build ----------------

__global__ void k_deg(const int* __restrict__ edge_dst, int* __restrict__ deg, int E) {
  int i = blockIdx.x * blockDim.x + threadIdx.x;
  if (i < E) atomicAdd(&deg[edge_dst[i]], 1);
}

__global__ void k_scan1(const int* __restrict__ deg, int* __restrict__ row_start,
                        int* __restrict__ blocksum, int N) {
  __shared__ int sm[SCAN_BS];
  int t = threadIdx.x;
  int base = blockIdx.x * SCAN_BS;
  int v = (base + t < N) ? deg[base + t] : 0;
  sm[t] = v;
  __syncthreads();
  for (int ofs = 1; ofs < SCAN_BS; ofs <<= 1) {
    int add = (t >= ofs) ? sm[t - ofs] : 0;
    __syncthreads();
    sm[t] += add;
    __syncthreads();
  }
  if (base + t < N) row_start[base + t] = sm[t] - v;
  if (t == SCAN_BS - 1) blocksum[blockIdx.x] = sm[t];
}

__global__ void k_scan2(int* __restrict__ blocksum, int nb) {
  __shared__ int sm[128];
  int t = threadIdx.x;
  int v = (t < nb) ? blocksum[t] : 0;
  sm[t] = v;
  __syncthreads();
  for (int ofs = 1; ofs < 128; ofs <<= 1) {
    int add = (t >= ofs) ? sm[t - ofs] : 0;
    __syncthreads();
    sm[t] += add;
    __syncthreads();
  }
  if (t < nb) blocksum[t] = sm[t] - v;
}

__global__ void k_scan3(int* __restrict__ row_start, const int* __restrict__ blocksum,
                        int* __restrict__ cursor, int N) {
  int n = blockIdx.x * blockDim.x + threadIdx.x;
  if (n < N) {
    int v = row_start[n] + blocksum[n / SCAN_BS];
    row_start[n] = v;
    cursor[n] = v;
  }
}

// ---------------- attention / gather / fill bodies ----------------

struct AttSmem {
  float r_lds[16 * NSLOT * D];   // 16KB
  float s_lds[16 * NSLOT];
  float m_lds[16 * NSLOT];
  float h_lds[NSLOT * D];
  float o_lds[NSLOT];
  int used[NSLOT];
  int sg_first;
};

__device__ __forceinline__ void att_body(AttSmem* sm, const float* __restrict__ F,
                                         const int* __restrict__ gid,
                                         const float* __restrict__ h,
                                         const float* __restrict__ off,
                                         unsigned* __restrict__ m_enc,
                                         float* __restrict__ s_buf,
                                         float* __restrict__ r_buf,
                                         int N, int bx) {
  const int tid = threadIdx.x;
  const int grp = tid >> 4;
  const int d4  = tid & 15;
  const int base = bx * NPB;

  for (int i = tid; i < 16 * NSLOT * D; i += 256) sm->r_lds[i] = 0.0f;
  if (tid < 16 * NSLOT) { sm->s_lds[tid] = 0.0f; sm->m_lds[tid] = -3.4e38f; }
  if (tid < NSLOT) sm->used[tid] = 0;
  if (tid == 0) sm->sg_first = gid[base];
  __syncthreads();
  const int gfirst = sm->sg_first;
  {
    int slot = tid >> 6, dim = tid & 63;
    int g = gfirst + slot;
    if (g < B) {
      sm->h_lds[tid] = h[g * D + dim];
      if (dim == 0) sm->o_lds[slot] = off[g];
    }
  }
  __syncthreads();

  float4 acc = make_float4(0.f, 0.f, 0.f, 0.f);
  float sum_ex = 0.0f;
  float local_max = -3.4e38f;
  int cur_g = -1;

  for (int itn = 0; itn < NPB / 32; ++itn) {
    int n0 = base + itn * 32 + grp;
    int n1 = n0 + 16;
    bool ok0 = n0 < N, ok1 = n1 < N;
    int g0 = ok0 ? gid[n0] : -1;
    int g1 = ok1 ? gid[n1] : -1;
    float4 f0 = make_float4(0,0,0,0), f1 = make_float4(0,0,0,0);
    float dot0 = 0.f, dot1 = 0.f, ex0 = 0.f, ex1 = 0.f;
    if (ok0) {
      f0 = *(const float4*)(F + (size_t)n0 * D + d4 * 4);
      int s0 = g0 - gfirst;
      float4 hv = (s0 >= 0 && s0 < NSLOT) ? *(const float4*)&sm->h_lds[(s0 << 6) + (d4 << 2)]
                                          : *(const float4*)(h + (size_t)g0 * D + d4 * 4);
      dot0 = f0.x * hv.x + f0.y * hv.y + f0.z * hv.z + f0.w * hv.w;
    }
    if (ok1) {
      f1 = *(const float4*)(F + (size_t)n1 * D + d4 * 4);
      int s1 = g1 - gfirst;
      float4 hv = (s1 >= 0 && s1 < NSLOT) ? *(const float4*)&sm->h_lds[(s1 << 6) + (d4 << 2)]
                                          : *(const float4*)(h + (size_t)g1 * D + d4 * 4);
      dot1 = f1.x * hv.x + f1.y * hv.y + f1.z * hv.z + f1.w * hv.w;
    }
    dot0 += __shfl_xor(dot0, 1); dot1 += __shfl_xor(dot1, 1);
    dot0 += __shfl_xor(dot0, 2); dot1 += __shfl_xor(dot1, 2);
    dot0 += __shfl_xor(dot0, 4); dot1 += __shfl_xor(dot1, 4);
    dot0 += __shfl_xor(dot0, 8); dot1 += __shfl_xor(dot1, 8);
    if (ok0) {
      int s0 = g0 - gfirst;
      ex0 = __expf(dot0 - ((s0 >= 0 && s0 < NSLOT) ? sm->o_lds[s0] : off[g0]));
    }
    if (ok1) {
      int s1 = g1 - gfirst;
      ex1 = __expf(dot1 - ((s1 >= 0 && s1 < NSLOT) ? sm->o_lds[s1] : off[g1]));
    }

    #pragma unroll
    for (int pair = 0; pair < 2; ++pair) {
      bool ok = pair ? ok1 : ok0;
      int g = pair ? g1 : g0;
      float ex = pair ? ex1 : ex0;
      float dt = pair ? dot1 : dot0;
      float4 f = pair ? f1 : f0;
      if (!ok) continue;
      if (g != cur_g) {
        if (cur_g >= 0) {
          int slot = cur_g - gfirst;
          if (slot >= 0 && slot < NSLOT) {
            float4* p = (float4*)&sm->r_lds[((grp * NSLOT + slot) << 6) + (d4 << 2)];
            float4 v = *p;
            v.x += acc.x; v.y += acc.y; v.z += acc.z; v.w += acc.w;
            *p = v;
            if (d4 == 0) {
              sm->s_lds[grp * NSLOT + slot] += sum_ex;
              sm->m_lds[grp * NSLOT + slot] = fmaxf(sm->m_lds[grp * NSLOT + slot], local_max);
              sm->used[slot] = 1;
            }
          } else {
            float* rp = r_buf + cur_g * D + d4 * 4;
            atomicAdd(rp + 0, acc.x); atomicAdd(rp + 1, acc.y);
            atomicAdd(rp + 2, acc.z); atomicAdd(rp + 3, acc.w);
            if (d4 == 0) { atomicAdd(&s_buf[cur_g], sum_ex); atomicMax(&m_enc[cur_g], encf(local_max)); }
          }
        }
        cur_g = g; acc = make_float4(0,0,0,0); sum_ex = 0.f; local_max = -3.4e38f;
      }
      acc.x += ex * f.x; acc.y += ex * f.y; acc.z += ex * f.z; acc.w += ex * f.w;
      if (d4 == 0) { sum_ex += ex; local_max = fmaxf(local_max, dt); }
    }
  }
  if (cur_g >= 0) {
    int slot = cur_g - gfirst;
    if (slot >= 0 && slot < NSLOT) {
      float4* p = (float4*)&sm->r_lds[((grp * NSLOT + slot) << 6) + (d4 << 2)];
      float4 v = *p;
      v.x += acc.x; v.y += acc.y; v.z += acc.z; v.w += acc.w;
      *p = v;
      if (d4 == 0) {
        sm->s_lds[grp * NSLOT + slot] += sum_ex;
        sm->m_lds[grp * NSLOT + slot] = fmaxf(sm->m_lds[grp * NSLOT + slot], local_max);
        sm->used[slot] = 1;
      }
    } else {
      float* rp = r_buf + cur_g * D + d4 * 4;
      atomicAdd(rp + 0, acc.x); atomicAdd(rp + 1, acc.y);
      atomicAdd(rp + 2, acc.z); atomicAdd(rp + 3, acc.w);
      if (d4 == 0) { atomicAdd(&s_buf[cur_g], sum_ex); atomicMax(&m_enc[cur_g], encf(local_max)); }
    }
  }
  __syncthreads();

  {
    int slot = tid >> 6, dim = tid & 63;
    int g = gfirst + slot;
    if (g < B && sm->used[slot]) {
      float sum = 0.0f;
      #pragma unroll
      for (int q = 0; q < 16; ++q) sum += sm->r_lds[((q * NSLOT + slot) << 6) + dim];
      atomicAdd(&r_buf[g * D + dim], sum);
    }
  }
  if (tid < NSLOT) {
    int g = gfirst + tid;
    if (g < B && sm->used[tid]) {
      float ssum = 0.0f;
      #pragma unroll
      for (int q = 0; q < 16; ++q) ssum += sm->s_lds[q * NSLOT + tid];
      atomicAdd(&s_buf[g], ssum);
    }
  } else if (tid >= 64 && tid < 64 + NSLOT) {
    int slot = tid - 64;
    int g = gfirst + slot;
    if (g < B && sm->used[slot]) {
      float mmax = -3.4e38f;
      #pragma unroll
      for (int q = 0; q < 16; ++q) mmax = fmaxf(mmax, sm->m_lds[q * NSLOT + slot]);
      atomicMax(&m_enc[g], encf(mmax));
    }
  }
}

__device__ __forceinline__ void gather_body(const float* __restrict__ efeat,
                                            const int* __restrict__ csr,
                                            const int* __restrict__ row_start,
                                            const int* __restrict__ deg,
                                            float* __restrict__ edge_agg, int N, int bx) {
  int grp = (bx * 256 + threadIdx.x) >> 4;
  int l16 = threadIdx.x & 15;
  if (grp >= N) return;
  int base = row_start[grp];
  int dg = deg[grp];
  float4 acc = make_float4(0.f, 0.f, 0.f, 0.f);
  for (int i = 0; i < dg; i += 16) {
    int idx[16];
    #pragma unroll
    for (int j = 0; j < 16; ++j) {
      int k = i + j;
      idx[j] = csr[base + (k < dg ? k : dg - 1)];
    }
    #pragma unroll
    for (int j = 0; j < 16; ++j) {
      float4 v = *(const float4*)(efeat + (size_t)idx[j] * D + l16 * 4);
      bool ok = (i + j < dg);
      acc.x += ok ? v.x : 0.0f;
      acc.y += ok ? v.y : 0.0f;
      acc.z += ok ? v.z : 0.0f;
      acc.w += ok ? v.w : 0.0f;
    }
  }
  float inv = 1.0f / fmaxf((float)dg, 1.0f);
  acc.x *= inv; acc.y *= inv; acc.z *= inv; acc.w *= inv;
  *(float4*)(edge_agg + (size_t)grp * D + l16 * 4) = acc;
}

// merged: blocks [0,ATT) att node-side; [ATT, ATT+FB) csr-fill
__global__ void k_att_fill(int ATT, const float* __restrict__ feat, const int* __restrict__ gid,
                           const float* __restrict__ h2, const float* __restrict__ off2,
                           unsigned* __restrict__ m2, float* __restrict__ s2,
                           float* __restrict__ r2, int N,
                           const int* __restrict__ edge_dst, int* __restrict__ cursor,
                           int* __restrict__ csr, int E) {
  __shared__ AttSmem sm;
  int bx = blockIdx.x;
  if (bx < ATT) {
    att_body(&sm, feat, gid, h2, off2, m2, s2, r2, N, bx);
  } else {
    int e = (bx - ATT) * 256 + threadIdx.x;
    if (e < E) {
      int dst = edge_dst[e];
      int idx = atomicAdd(&cursor[dst], 1);
      csr[idx] = e;
    }
  }
}

// merged: blocks [0,ATT) att node-side; [ATT, ATT+GB) gather
__global__ void k_att_gather(int ATT, const float* __restrict__ feat, const int* __restrict__ gid,
                             const float* __restrict__ h2, const float* __restrict__ off2,
                             unsigned* __restrict__ m2, float* __restrict__ s2,
                             float* __restrict__ r2, int N,
                             const float* __restrict__ efeat, const int* __restrict__ csr,
                             const int* __restrict__ row_start, const int* __restrict__ deg,
                             float* __restrict__ edge_agg) {
  __shared__ AttSmem sm;
  int bx = blockIdx.x;
  if (bx < ATT) {
    att_body(&sm, feat, gid, h2, off2, m2, s2, r2, N, bx);
  } else {
    gather_body(efeat, csr, row_start, deg, edge_agg, N, bx - ATT);
  }
}

// plain att: side = blockIdx.y + side_base
__global__ void k_att(int side_base, const float* __restrict__ feat,
                      const float* __restrict__ edge_agg, const int* __restrict__ gid,
                      const float* __restrict__ h2, const float* __restrict__ off2,
                      unsigned* __restrict__ m2, float* __restrict__ s2,
                      float* __restrict__ r2, int N) {
  __shared__ AttSmem sm;
  int side = blockIdx.y + side_base;
  att_body(&sm, side ? edge_agg : feat, gid, h2 + side * B * D, off2 + side * B,
           m2 + side * B, s2 + side * B, r2 + side * B * D, N, blockIdx.x);
}

// ---------------- LSTM: side = blockIdx.y + side_base, first per side -------

__global__ void k_lstm(int firstN, int firstE, int side_base,
                       float* __restrict__ h2, float* __restrict__ c2,
                       float* __restrict__ s2, float* __restrict__ r2,
                       unsigned* __restrict__ m2, float* __restrict__ off2,
                       const float* __restrict__ nWih, const float* __restrict__ nWhh,
                       const float* __restrict__ nbih, const float* __restrict__ nbhh,
                       const float* __restrict__ eWih, const float* __restrict__ eWhh,
                       const float* __restrict__ ebih, const float* __restrict__ ebhh) {
  __shared__ float sq[2 * D], sg[4 * D];
  int side = blockIdx.y + side_base;
  int first = side ? firstE : firstN;
  const float* Wih = side ? eWih : nWih;
  const float* Whh = side ? eWhh : nWhh;
  const float* bih = side ? ebih : nbih;
  const float* bhh = side ? ebhh : nbhh;
  float* h = h2 + side * B * D;
  float* c = c2 + side * B * D;
  float* s_buf = s2 + side * B;
  float* r_buf = r2 + side * B * D;

  int b = blockIdx.x, j = threadIdx.x;
  if (j < D) {
    sq[j] = h[b * D + j];
  } else if (j < 2 * D) {
    sq[j] = first ? 0.0f : (r_buf[b * D + (j - D)] / s_buf[b]);
  }
  __syncthreads();
  float acc = bih[j] + bhh[j];
  const float* wr = Wih + (size_t)j * (2 * D);
  #pragma unroll 8
  for (int k = 0; k < 2 * D; ++k) acc += sq[k] * wr[k];
  const float* wr2 = Whh + (size_t)j * D;
  #pragma unroll 8
  for (int k = 0; k < D; ++k) acc += sq[k] * wr2[k];
  sg[j] = acc;
  __syncthreads();
  if (j < D) {
    float ig = sigm(sg[j]);
    float fg = sigm(sg[D + j]);
    float gg = tanhf(sg[2 * D + j]);
    float og = sigm(sg[3 * D + j]);
    float cn = fg * c[b * D + j] + ig * gg;
    c[b * D + j] = cn;
    h[b * D + j] = og * tanhf(cn);
    r_buf[b * D + j] = 0.0f;
  }
  if (j == D) s_buf[b] = 0.0f;
  if (j == D + 1) {
    int idx = side * B + b;
    off2[idx] = first ? 0.0f : decf(m2[idx]);
    m2[idx] = 0u;
  }
}

// ---------------- MLP ----------------

__global__ void k_mlp(const float* __restrict__ h2, const float* __restrict__ r2,
                      const float* __restrict__ s2,
                      const float* __restrict__ W1, const float* __restrict__ b1,
                      const float* __restrict__ W2, const float* __restrict__ b2,
                      const float* __restrict__ W3, const float* __restrict__ b3,
                      float* __restrict__ out) {
  __shared__ float x[4 * D], h1[32], h2s[16];
  int b = blockIdx.x, t = threadIdx.x;   // 128 threads
  x[t]       = (t < D) ? h2[b * D + t]         : r2[b * D + (t - D)] / s2[b];
  x[128 + t] = (t < D) ? h2[B * D + b * D + t] : r2[B * D + b * D + (t - D)] / s2[B + b];
  __syncthreads();
  if (t < 32) {
    float acc = b1[t];
    const float* w = W1 + (size_t)t * (4 * D);
    #pragma unroll 8
    for (int k = 0; k < 4 * D; ++k) acc += x[k] * w[k];
    h1[t] = fmaxf(acc, 0.0f);
  }
  __syncthreads();
  if (t < 16) {
    float acc = b2[t];
    const float* w = W2 + (size_t)t * 32;
    #pragma unroll
    for (int k = 0; k < 32; ++k) acc += h1[k] * w[k];
    h2s[t] = fmaxf(acc, 0.0f);
  }
  __syncthreads();
  if (t == 0) {
    float acc = b3[0];
    #pragma unroll
    for (int k = 0; k < 16; ++k) acc += h2s[k] * W3[k];
    out[b] = acc;
  }
}

// ---------------- driver ----------------

extern "C" void kernel_launch(void* const* d_in, const int* in_sizes, int n_in,
                              void* d_out, int out_size, void* d_ws, size_t ws_size,
                              hipStream_t stream) {
  const float* feat      = (const float*)d_in[0];
  const float* efeat     = (const float*)d_in[1];
  const int*   edge_dst  = (const int*)d_in[2];
  const int*   node_graph= (const int*)d_in[3];
  const float* node_Wih  = (const float*)d_in[5];
  const float* node_Whh  = (const float*)d_in[6];
  const float* node_bih  = (const float*)d_in[7];
  const float* node_bhh  = (const float*)d_in[8];
  const float* edge_Wih  = (const float*)d_in[9];
  const float* edge_Whh  = (const float*)d_in[10];
  const float* edge_bih  = (const float*)d_in[11];
  const float* edge_bhh  = (const float*)d_in[12];
  const float* W1 = (const float*)d_in[13];
  const float* b1 = (const float*)d_in[14];
  const float* W2 = (const float*)d_in[15];
  const float* b2 = (const float*)d_in[16];
  const float* W3 = (const float*)d_in[17];
  const float* b3 = (const float*)d_in[18];
  float* out = (float*)d_out;

  const int N = in_sizes[0] / D;
  const int E = in_sizes[2];

  // ws layout
  float* ws = (float*)d_ws;
  size_t off = 0;
  float* edge_agg = ws + off; off += (size_t)N * D;
  float* h2       = ws + off; off += 2 * B * D;
  float* c2       = ws + off; off += 2 * B * D;
  float* s2       = ws + off; off += 2 * B;
  float* r2       = ws + off; off += 2 * B * D;
  float* off2     = ws + off; off += 2 * B;
  unsigned* m2    = (unsigned*)(ws + off); off += 2 * B;
  int* deg        = (int*)(ws + off); off += N;
  int* row_start  = (int*)(ws + off); off += N;
  int* cursor     = (int*)(ws + off); off += N;
  int* blocksum   = (int*)(ws + off); off += 128;
  int* csr        = (int*)(ws + off); off += E + 8;

  hipMemsetAsync(deg, 0, (size_t)N * sizeof(int), stream);
  hipMemsetAsync(h2, 0, (size_t)(4 * B * D) * sizeof(float), stream);  // h2+c2

  const int nb = (N + SCAN_BS - 1) / SCAN_BS;
  const int ATT = (N + NPB - 1) / NPB;          // 782
  const int FB = (E + 255) / 256;               // fill blocks
  const int GB = (N + 15) / 16;                 // gather blocks

  // CSR prefix (deg+scan) — needed before fill
  k_deg<<<(E + 255) / 256, 256, 0, stream>>>(edge_dst, deg, E);
  k_scan1<<<nb, SCAN_BS, 0, stream>>>(deg, row_start, blocksum, N);
  k_scan2<<<1, 128, 0, stream>>>(blocksum, nb);
  k_scan3<<<(N + 255) / 256, 256, 0, stream>>>(row_start, blocksum, cursor, N);

  // node it0 LSTM
  k_lstm<<<dim3(B, 1), 256, 0, stream>>>(1, 0, 0, h2, c2, s2, r2, m2, off2,
      node_Wih, node_Whh, node_bih, node_bhh, edge_Wih, edge_Whh, edge_bih, edge_bhh);
  // node att0  ||  csr fill
  k_att_fill<<<ATT + FB, 256, 0, stream>>>(ATT, feat, node_graph, h2, off2, m2, s2, r2, N,
      edge_dst, cursor, csr, E);
  // node it1 LSTM
  k_lstm<<<dim3(B, 1), 256, 0, stream>>>(0, 0, 0, h2, c2, s2, r2, m2, off2,
      node_Wih, node_Whh, node_bih, node_bhh, edge_Wih, edge_Whh, edge_bih, edge_bhh);
  // node att1  ||  gather
  k_att_gather<<<ATT + GB, 256, 0, stream>>>(ATT, feat, node_graph, h2, off2, m2, s2, r2, N,
      efeat, csr, row_start, deg, edge_agg);
  // node it2 + edge it0 LSTM
  k_lstm<<<dim3(B, 2), 256, 0, stream>>>(0, 1, 0, h2, c2, s2, r2, m2, off2,
      node_Wih, node_Whh, node_bih, node_bhh, edge_Wih, edge_Whh, edge_bih, edge_bhh);
  // node att2 + edge att0
  k_att<<<dim3(ATT, 2), 256, 0, stream>>>(0, feat, edge_agg, node_graph, h2, off2, m2, s2, r2, N);
  // edge it1
  k_lstm<<<dim3(B, 1), 256, 0, stream>>>(0, 0, 1, h2, c2, s2, r2, m2, off2,
      node_Wih, node_Whh, node_bih, node_bhh, edge_Wih, edge_Whh, edge_bih, edge_bhh);
  k_att<<<dim3(ATT, 1), 256, 0, stream>>>(1, feat, edge_agg, node_graph, h2, off2, m2, s2, r2, N);
  // edge it2
  k_lstm<<<dim3(B, 1), 256, 0, stream>>>(0, 0, 1, h2, c2, s2, r2, m2, off2,
      node_Wih, node_Whh, node_bih, node_bhh, edge_Wih, edge_Whh, edge_bih, edge_bhh);
  k_att<<<dim3(ATT, 1), 256, 0, stream>>>(1, feat, edge_agg, node_graph, h2, off2, m2, s2, r2, N);

  k_mlp<<<B, 128, 0, stream>>>(h2, r2, s2, W1, b1, W2, b2, W3, b3, out);
}